// Round 16
// baseline (96.694 us; speedup 1.0000x reference)
//
#include <hip/hip_runtime.h>
#include <hip/hip_bf16.h>

#define C_DIM 512
#define L_DIM 1024
#define KK 64
#define KG 65
#define KP 80   // padded k rows (5 tiles of 16)

using f32x4  = __attribute__((ext_vector_type(4))) float;
using bf16x8 = __attribute__((ext_vector_type(8))) short;

union U4 { uint4 u; bf16x8 b; };

__device__ __forceinline__ unsigned bfh(float x) { return __float_as_uint(x) >> 16; }
__device__ __forceinline__ float bfh_f(float x) { return __uint_as_float(__float_as_uint(x) & 0xFFFF0000u); }

// pack two fp32 -> word of 2 bf16 (truncation): low16 = a, high16 = b
__device__ __forceinline__ unsigned pack2(float a, float b) {
    return __builtin_amdgcn_perm(__float_as_uint(b), __float_as_uint(a), 0x07060302u);
}

#define PB 2688   // floats per (block,wave) partial record: 10*256 acc + 128 ss

// ---------------- prep: split conv_w into bf16 hi/lo IN MFMA FRAGMENT ORDER ----------
__global__ void k_prep(const float* __restrict__ conv_w, const float* __restrict__ conv_b,
                       unsigned short* __restrict__ wpH, unsigned short* __restrict__ wpL,
                       float* __restrict__ wb)
{
    int ch = blockIdx.x;          // 0..15
    int kt = blockIdx.y;          // 0..4
    int t  = threadIdx.x;         // 0..255
    for (int p = 0; p < 2; ++p) {
        int idx = p * 256 + t;    // 0..511
        int lane = idx >> 3, j = idx & 7;
        int k = kt * 16 + (lane & 15);
        int c = ch * 32 + (lane >> 4) * 8 + j;
        float v = (k < KG) ? conv_w[k * C_DIM + c] : 0.f;
        unsigned h = bfh(v);
        float r = v - __uint_as_float(h << 16);
        int pos = ((ch * 5 + kt) << 9) + idx;
        wpH[pos] = (unsigned short)h;
        wpL[pos] = (unsigned short)bfh(r);
    }
    if (ch == 0 && kt == 0 && t < KP) wb[t] = (t < KG) ? conv_b[t] : -1e30f;
}

// ---------------- Stage 1a: partial logits over a c-half (R13 mix, 2x waves) --------
// Grid (16, 64): blockIdx.x = lb*2 + chalf. Block 256 = 4 waves, wave owns 32 l.
// Identical per-chunk instruction mix to the R13 kernel, but 4096 waves (4/SIMD)
// to halve exposed latency. Partials written with coalesced 1KB float4 stores.
__global__ __launch_bounds__(256) void k_s1a(
    const float* __restrict__ x, const unsigned short* __restrict__ wpH,
    const unsigned short* __restrict__ wpL, float* __restrict__ pacc)
{
    const int bx = blockIdx.x, n = blockIdx.y;
    const int lb = bx >> 1, chalf = bx & 1;
    const int t = threadIdx.x, lane = t & 63, w = t >> 6;
    const int arow = lane & 15;
    const int agrp = lane >> 4;
    const int lw0 = lb * 128 + w * 32;

    const float* xbase = x + (size_t)n * C_DIM * L_DIM;

    f32x4 acc[5][2];
#pragma unroll
    for (int a = 0; a < 5; ++a)
#pragma unroll
        for (int b = 0; b < 2; ++b) acc[a][b] = (f32x4)0.f;
    float ss0 = 0.f, ss1 = 0.f;

    for (int ch8 = 0; ch8 < 8; ++ch8) {
        const int ch = chalf * 8 + ch8;
        const int c0 = ch * 32;
        float e0[8], e1[8];
#pragma unroll
        for (int j = 0; j < 8; ++j) {
            const float* col = &xbase[(size_t)(c0 + agrp * 8 + j) * L_DIM + lw0 + arow];
            e0[j] = col[0];
            e1[j] = col[16];
        }
#pragma unroll
        for (int j = 0; j < 8; ++j) { ss0 += e0[j] * e0[j]; ss1 += e1[j] * e1[j]; }
        U4 bh[2], bl[2];
        bh[0].u.x = pack2(e0[0], e0[1]); bh[0].u.y = pack2(e0[2], e0[3]);
        bh[0].u.z = pack2(e0[4], e0[5]); bh[0].u.w = pack2(e0[6], e0[7]);
        bh[1].u.x = pack2(e1[0], e1[1]); bh[1].u.y = pack2(e1[2], e1[3]);
        bh[1].u.z = pack2(e1[4], e1[5]); bh[1].u.w = pack2(e1[6], e1[7]);
        float r0, r1, r2, r3;
        r0 = e0[0] - bfh_f(e0[0]); r1 = e0[1] - bfh_f(e0[1]);
        r2 = e0[2] - bfh_f(e0[2]); r3 = e0[3] - bfh_f(e0[3]);
        bl[0].u.x = pack2(r0, r1); bl[0].u.y = pack2(r2, r3);
        r0 = e0[4] - bfh_f(e0[4]); r1 = e0[5] - bfh_f(e0[5]);
        r2 = e0[6] - bfh_f(e0[6]); r3 = e0[7] - bfh_f(e0[7]);
        bl[0].u.z = pack2(r0, r1); bl[0].u.w = pack2(r2, r3);
        r0 = e1[0] - bfh_f(e1[0]); r1 = e1[1] - bfh_f(e1[1]);
        r2 = e1[2] - bfh_f(e1[2]); r3 = e1[3] - bfh_f(e1[3]);
        bl[1].u.x = pack2(r0, r1); bl[1].u.y = pack2(r2, r3);
        r0 = e1[4] - bfh_f(e1[4]); r1 = e1[5] - bfh_f(e1[5]);
        r2 = e1[6] - bfh_f(e1[6]); r3 = e1[7] - bfh_f(e1[7]);
        bl[1].u.z = pack2(r0, r1); bl[1].u.w = pack2(r2, r3);
        U4 ah[5], al[5];
#pragma unroll
        for (int kt = 0; kt < 5; ++kt) {
            int poff = (((ch * 5 + kt) << 6) + lane) << 3;
            ah[kt].u = *reinterpret_cast<const uint4*>(&wpH[poff]);
            al[kt].u = *reinterpret_cast<const uint4*>(&wpL[poff]);
        }
#pragma unroll
        for (int kt = 0; kt < 5; ++kt)
#pragma unroll
            for (int lt = 0; lt < 2; ++lt) {
                acc[kt][lt] = __builtin_amdgcn_mfma_f32_16x16x32_bf16(ah[kt].b, bh[lt].b, acc[kt][lt], 0, 0, 0);
                acc[kt][lt] = __builtin_amdgcn_mfma_f32_16x16x32_bf16(ah[kt].b, bl[lt].b, acc[kt][lt], 0, 0, 0);
                acc[kt][lt] = __builtin_amdgcn_mfma_f32_16x16x32_bf16(al[kt].b, bh[lt].b, acc[kt][lt], 0, 0, 0);
            }
    }

    // ---- write partials: coalesced 1KB float4 stores
    float* p = pacc + ((size_t)(n * 16 + bx) * 4 + w) * PB;
#pragma unroll
    for (int kt = 0; kt < 5; ++kt)
#pragma unroll
        for (int lt = 0; lt < 2; ++lt)
            *reinterpret_cast<float4*>(&p[(kt * 2 + lt) * 256 + lane * 4]) =
                make_float4(acc[kt][lt][0], acc[kt][lt][1], acc[kt][lt][2], acc[kt][lt][3]);
    *reinterpret_cast<float2*>(&p[2560 + lane * 2]) = make_float2(ss0, ss1);
}

// ---------------- Stage 1b: combine halves + norm + softmax + aP/asum (R13 epilogue) --
__global__ __launch_bounds__(256) void k_s1b(
    const float* __restrict__ pacc, const float* __restrict__ wb,
    unsigned short* __restrict__ aPh, unsigned short* __restrict__ aPl,
    float* __restrict__ asum_part)
{
    const int lb = blockIdx.x, n = blockIdx.y;
    const int t = threadIdx.x, lane = t & 63, w = t >> 6;
    const int arow = lane & 15;
    const int agrp = lane >> 4;
    const int lw0 = lb * 128 + w * 32;

    f32x4 acc[5][2];
    float ss0 = 0.f, ss1 = 0.f;
#pragma unroll
    for (int a = 0; a < 5; ++a)
#pragma unroll
        for (int b = 0; b < 2; ++b) acc[a][b] = (f32x4)0.f;
#pragma unroll
    for (int chalf = 0; chalf < 2; ++chalf) {
        const float* p = pacc + ((size_t)(n * 16 + lb * 2 + chalf) * 4 + w) * PB;
#pragma unroll
        for (int kt = 0; kt < 5; ++kt)
#pragma unroll
            for (int lt = 0; lt < 2; ++lt) {
                float4 v = *reinterpret_cast<const float4*>(&p[(kt * 2 + lt) * 256 + lane * 4]);
                acc[kt][lt][0] += v.x; acc[kt][lt][1] += v.y;
                acc[kt][lt][2] += v.z; acc[kt][lt][3] += v.w;
            }
        float2 sv = *reinterpret_cast<const float2*>(&p[2560 + lane * 2]);
        ss0 += sv.x; ss1 += sv.y;
    }

    ss0 += __shfl_xor(ss0, 16, 64); ss0 += __shfl_xor(ss0, 32, 64);
    ss1 += __shfl_xor(ss1, 16, 64); ss1 += __shfl_xor(ss1, 32, 64);
    float invc[2];
    invc[0] = 1.0f / fmaxf(sqrtf(ss0), 1e-12f);
    invc[1] = 1.0f / fmaxf(sqrtf(ss1), 1e-12f);

    float4 wbv[5];
#pragma unroll
    for (int kt = 0; kt < 5; ++kt)
        wbv[kt] = *reinterpret_cast<const float4*>(&wb[kt * 16 + agrp * 4]);

    float aval[5][2][4];
    float rs[2];
#pragma unroll
    for (int lt = 0; lt < 2; ++lt) {
        float m = -1e30f;
#pragma unroll
        for (int kt = 0; kt < 5; ++kt)
#pragma unroll
            for (int r = 0; r < 4; ++r) {
                float lg = acc[kt][lt][r] * invc[lt] + ((const float*)&wbv[kt])[r];
                aval[kt][lt][r] = lg;
                m = fmaxf(m, lg);
            }
        m = fmaxf(m, __shfl_xor(m, 16, 64));
        m = fmaxf(m, __shfl_xor(m, 32, 64));
        float s = 0.f;
#pragma unroll
        for (int kt = 0; kt < 5; ++kt)
#pragma unroll
            for (int r = 0; r < 4; ++r) {
                float e = __expf(aval[kt][lt][r] - m);
                aval[kt][lt][r] = e;
                s += e;
            }
        s += __shfl_xor(s, 16, 64);
        s += __shfl_xor(s, 32, 64);
        rs[lt] = 1.0f / s;
    }

#pragma unroll
    for (int kt = 0; kt < 4; ++kt)
#pragma unroll
        for (int r = 0; r < 4; ++r) {
            int k = kt * 16 + agrp * 4 + r;
            float s01 = 0.f;
#pragma unroll
            for (int lt = 0; lt < 2; ++lt) {
                float a = aval[kt][lt][r] * rs[lt];
                aval[kt][lt][r] = a;
                s01 += a;
            }
#pragma unroll
            for (int off = 8; off; off >>= 1) s01 += __shfl_xor(s01, off, 64);
            if ((lane & 15) == 0)
                asum_part[((n * 8 + lb) * 4 + w) * KK + k] = s01;
#pragma unroll
            for (int lt = 0; lt < 2; ++lt) {
                float ap = aval[kt][lt][r] * invc[lt];
                unsigned h = bfh(ap);
                float res = ap - __uint_as_float(h << 16);
                int idx = (n * KK + k) * L_DIM + lw0 + lt * 16 + arow;
                aPh[idx] = (unsigned short)h;
                aPl[idx] = (unsigned short)bfh(res);
            }
        }
}

// ---------------- Stage 2: weighted = a' x^T, LDS-staged MFMA GEMM + XCD swizzle -----
#define S2P 72   // LDS row pitch in shorts (144 B, 16B-aligned rows)
__global__ __launch_bounds__(256) void k_s2(
    const float* __restrict__ x, const unsigned short* __restrict__ aPh,
    const unsigned short* __restrict__ aPl, float* __restrict__ weighted)
{
    __shared__ unsigned short Ah[64 * S2P], Al[64 * S2P];   // aP chunk [k][l]
    __shared__ unsigned short Bh[64 * S2P], Bl[64 * S2P];   // x  chunk [c][l]

    const int flat = blockIdx.x;
    const int cq = flat >> 6;                               // 0..7
    const int n  = ((flat & 7) << 3) | ((flat >> 3) & 7);   // bijective, XCD-pinned
    const int t = threadIdx.x, lane = t & 63, w = t >> 6;
    const int arow = lane & 15, agrp = lane >> 4;

    f32x4 acc[4];
#pragma unroll
    for (int a = 0; a < 4; ++a) acc[a] = (f32x4)0.f;

    for (int step = 0; step < 16; ++step) {
        const int l0 = step * 64;
        __syncthreads();   // previous iter's reads done before restage
#pragma unroll
        for (int p = 0; p < 2; ++p) {
            int idx = p * 256 + t;          // 0..511 (512 uint4 = 4096 shorts)
            int k = idx >> 3;               // 8 uint4 per 64-short row
            int lc = (idx & 7) * 8;
            size_t g = (size_t)(n * KK + k) * L_DIM + l0 + lc;
            *reinterpret_cast<uint4*>(&Ah[k * S2P + lc]) = *reinterpret_cast<const uint4*>(&aPh[g]);
            *reinterpret_cast<uint4*>(&Al[k * S2P + lc]) = *reinterpret_cast<const uint4*>(&aPl[g]);
        }
#pragma unroll
        for (int p = 0; p < 4; ++p) {
            int idx = p * 256 + t;          // 0..1023 (1024 float4)
            int c = idx >> 4;               // 16 float4 per 64-float row
            int lc = (idx & 15) * 4;
            float4 v = *reinterpret_cast<const float4*>(
                &x[((size_t)n * C_DIM + cq * 64 + c) * L_DIM + l0 + lc]);
            uint2 hw, lw;
            hw.x = pack2(v.x, v.y); hw.y = pack2(v.z, v.w);
            float r0 = v.x - bfh_f(v.x), r1 = v.y - bfh_f(v.y);
            float r2 = v.z - bfh_f(v.z), r3 = v.w - bfh_f(v.w);
            lw.x = pack2(r0, r1); lw.y = pack2(r2, r3);
            *reinterpret_cast<uint2*>(&Bh[c * S2P + lc]) = hw;
            *reinterpret_cast<uint2*>(&Bl[c * S2P + lc]) = lw;
        }
        __syncthreads();
#pragma unroll
        for (int ks = 0; ks < 2; ++ks) {
            const int koff = ks * 32 + agrp * 8;
            U4 bh, bl;
            bh.u = *reinterpret_cast<const uint4*>(&Bh[(w * 16 + arow) * S2P + koff]);
            bl.u = *reinterpret_cast<const uint4*>(&Bl[(w * 16 + arow) * S2P + koff]);
#pragma unroll
            for (int kt = 0; kt < 4; ++kt) {
                U4 ah, al;
                ah.u = *reinterpret_cast<const uint4*>(&Ah[(kt * 16 + arow) * S2P + koff]);
                al.u = *reinterpret_cast<const uint4*>(&Al[(kt * 16 + arow) * S2P + koff]);
                acc[kt] = __builtin_amdgcn_mfma_f32_16x16x32_bf16(ah.b, bh.b, acc[kt], 0, 0, 0);
                acc[kt] = __builtin_amdgcn_mfma_f32_16x16x32_bf16(ah.b, bl.b, acc[kt], 0, 0, 0);
                acc[kt] = __builtin_amdgcn_mfma_f32_16x16x32_bf16(al.b, bh.b, acc[kt], 0, 0, 0);
            }
        }
    }
#pragma unroll
    for (int kt = 0; kt < 4; ++kt)
#pragma unroll
        for (int r = 0; r < 4; ++r) {
            int k = kt * 16 + agrp * 4 + r;
            weighted[((size_t)n * KK + k) * C_DIM + cq * 64 + w * 16 + arow] = acc[kt][r];
        }
}

// ---------------- per-(n,k): a_sum + row sumsq of vlad ----------------
__global__ void k_rownorm(const float* __restrict__ weighted, const float* __restrict__ part,
                          const float* __restrict__ cent, float* __restrict__ a_sum,
                          float* __restrict__ rn)
{
    int nk = blockIdx.x;          // 0..4095
    int n = nk >> 6, k = nk & 63;
    int t = threadIdx.x;          // 256
    float as = 0.f;
#pragma unroll
    for (int p = 0; p < 32; ++p) as += part[(n * 32 + p) * KK + k];
    if (t == 0) a_sum[nk] = as;
    float s = 0.f;
    for (int c = t; c < C_DIM; c += 256) {
        float v = weighted[(size_t)nk * C_DIM + c] - as * cent[k * C_DIM + c];
        s += v * v;
    }
#pragma unroll
    for (int off = 32; off; off >>= 1) s += __shfl_down(s, off, 64);
    __shared__ float red[4];
    if ((t & 63) == 0) red[t >> 6] = s;
    __syncthreads();
    if (t == 0) rn[nk] = red[0] + red[1] + red[2] + red[3];
}

// ---------------- per-n global norm -> combined scale ----------------
__global__ void k_scale(const float* __restrict__ rn, float* __restrict__ scale)
{
    int n = blockIdx.x;
    int k = threadIdx.x;    // 64
    float s = rn[n * 64 + k];
    float nrm = sqrtf(s);
    float den = fmaxf(nrm, 1e-12f);
    float tk = nrm / den;
    float tot = tk * tk;
#pragma unroll
    for (int off = 32; off; off >>= 1) tot += __shfl_down(tot, off, 64);
    tot = __shfl(tot, 0, 64);
    float g = fmaxf(sqrtf(tot), 1e-12f);
    scale[n * 64 + k] = 1.0f / (den * g);
}

// ---------------- final output ----------------
__global__ void k_out(const float* __restrict__ weighted, const float* __restrict__ a_sum,
                      const float* __restrict__ cent, const float* __restrict__ scale,
                      float* __restrict__ out)
{
    int nk = blockIdx.x;
    int k = nk & 63;
    int t = threadIdx.x;
    float as = a_sum[nk];
    float sc = scale[nk];
    for (int c = t; c < C_DIM; c += 256) {
        float v = weighted[(size_t)nk * C_DIM + c] - as * cent[k * C_DIM + c];
        out[(size_t)nk * C_DIM + c] = v * sc;
    }
}

extern "C" void kernel_launch(void* const* d_in, const int* in_sizes, int n_in,
                              void* d_out, int out_size, void* d_ws, size_t ws_size,
                              hipStream_t stream)
{
    const float* x    = (const float*)d_in[0];
    const float* cent = (const float*)d_in[1];
    const float* cw   = (const float*)d_in[2];
    const float* cb   = (const float*)d_in[3];
    float* out = (float*)d_out;
    char* ws = (char*)d_ws;

    unsigned short* wpH = (unsigned short*)(ws + 0);                // 80 KB packed
    unsigned short* wpL = (unsigned short*)(ws + 131072);           // 80 KB packed
    float*          wb  = (float*)(ws + 262144);                    // 320 B
    unsigned short* aPh = (unsigned short*)(ws + 524288);           // 8 MB
    unsigned short* aPl = (unsigned short*)(ws + 8912896);          // 8 MB
    float* asum_part    = (float*)(ws + 17301504);                  // 512 KB
    float* a_sum        = (float*)(ws + 17825792);                  // 16 KB
    float* weighted     = (float*)(ws + 18874368);                  // 8 MB
    float* rn           = (float*)(ws + 35651584);
    float* scale        = (float*)(ws + 35667968);
    float* pacc         = (float*)(ws + 37748736);                  // 44 MB partials

    k_prep<<<dim3(16, 5), 256, 0, stream>>>(cw, cb, wpH, wpL, wb);
    k_s1a<<<dim3(16, 64), 256, 0, stream>>>(x, wpH, wpL, pacc);
    k_s1b<<<dim3(8, 64), 256, 0, stream>>>(pacc, wb, aPh, aPl, asum_part);
    k_s2<<<512, 256, 0, stream>>>(x, aPh, aPl, weighted);
    k_rownorm<<<4096, 256, 0, stream>>>(weighted, asum_part, cent, a_sum, rn);
    k_scale<<<64, 64, 0, stream>>>(rn, scale);
    k_out<<<4096, 256, 0, stream>>>(weighted, a_sum, cent, scale, out);
}

// Round 17
// 77.906 us; speedup vs baseline: 1.2412x; 1.2412x over previous
//
#include <hip/hip_runtime.h>
#include <hip/hip_bf16.h>

#define C_DIM 512
#define L_DIM 1024
#define KK 64
#define KG 65
#define KP 80   // padded k rows (5 tiles of 16)

using f32x4  = __attribute__((ext_vector_type(4))) float;
using bf16x8 = __attribute__((ext_vector_type(8))) short;

union U4 { uint4 u; bf16x8 b; };

__device__ __forceinline__ unsigned bfh(float x) { return __float_as_uint(x) >> 16; }
__device__ __forceinline__ float bfh_f(float x) { return __uint_as_float(__float_as_uint(x) & 0xFFFF0000u); }

// pack two fp32 -> word of 2 bf16 (truncation): low16 = a, high16 = b
__device__ __forceinline__ unsigned pack2(float a, float b) {
    return __builtin_amdgcn_perm(__float_as_uint(b), __float_as_uint(a), 0x07060302u);
}

// ---------------- prep: split conv_w into bf16 hi/lo IN MFMA FRAGMENT ORDER ----------
__global__ void k_prep(const float* __restrict__ conv_w, const float* __restrict__ conv_b,
                       unsigned short* __restrict__ wpH, unsigned short* __restrict__ wpL,
                       float* __restrict__ wb)
{
    int ch = blockIdx.x;          // 0..15
    int kt = blockIdx.y;          // 0..4
    int t  = threadIdx.x;         // 0..255
    for (int p = 0; p < 2; ++p) {
        int idx = p * 256 + t;    // 0..511
        int lane = idx >> 3, j = idx & 7;
        int k = kt * 16 + (lane & 15);
        int c = ch * 32 + (lane >> 4) * 8 + j;
        float v = (k < KG) ? conv_w[k * C_DIM + c] : 0.f;
        unsigned h = bfh(v);
        float r = v - __uint_as_float(h << 16);
        int pos = ((ch * 5 + kt) << 9) + idx;
        wpH[pos] = (unsigned short)h;
        wpL[pos] = (unsigned short)bfh(r);
    }
    if (ch == 0 && kt == 0 && t < KP) wb[t] = (t < KG) ? conv_b[t] : -1e30f;
}

// ---------------- Stage 1: packed weights + paired-l float2 loads + packed stores ----
// Grid (8 lb, 64 n), block 256 = 4 waves. Wave owns 32 l as two interleaved tiles:
// tile lt covers l = lw0 + 2*arow + lt. One float2 load feeds both tiles (8 loads
// per chunk, 4 full 128B lines each); epilogue packs the two adjacent-l bf16 into
// ONE u32 store (dense 64B segments) -- buffer layout identical to linear aPh/aPl.
__global__ __launch_bounds__(256) void k_s1(
    const float* __restrict__ x, const unsigned short* __restrict__ wpH,
    const unsigned short* __restrict__ wpL, const float* __restrict__ wb,
    unsigned* __restrict__ aPh32, unsigned* __restrict__ aPl32,
    float* __restrict__ asum_part)
{
    const int lb = blockIdx.x, n = blockIdx.y;
    const int t = threadIdx.x, lane = t & 63, w = t >> 6;
    const int arow = lane & 15;          // A/C row & B col within tile
    const int agrp = lane >> 4;          // k-slice group
    const int lw0 = lb * 128 + w * 32;   // global l base of wave

    const float* xbase = x + (size_t)n * C_DIM * L_DIM;

    f32x4 acc[5][2];
#pragma unroll
    for (int a = 0; a < 5; ++a)
#pragma unroll
        for (int b = 0; b < 2; ++b) acc[a][b] = (f32x4)0.f;
    float ss0 = 0.f, ss1 = 0.f;

    for (int ch = 0; ch < 16; ++ch) {
        const int c0 = ch * 32;
        float e0[8], e1[8];
#pragma unroll
        for (int j = 0; j < 8; ++j) {
            float2 v = *reinterpret_cast<const float2*>(
                &xbase[(size_t)(c0 + agrp * 8 + j) * L_DIM + lw0 + 2 * arow]);
            e0[j] = v.x;     // l = lw0 + 2*arow     (tile 0)
            e1[j] = v.y;     // l = lw0 + 2*arow + 1 (tile 1)
        }
#pragma unroll
        for (int j = 0; j < 8; ++j) { ss0 += e0[j] * e0[j]; ss1 += e1[j] * e1[j]; }
        U4 bh[2], bl[2];
        bh[0].u.x = pack2(e0[0], e0[1]); bh[0].u.y = pack2(e0[2], e0[3]);
        bh[0].u.z = pack2(e0[4], e0[5]); bh[0].u.w = pack2(e0[6], e0[7]);
        bh[1].u.x = pack2(e1[0], e1[1]); bh[1].u.y = pack2(e1[2], e1[3]);
        bh[1].u.z = pack2(e1[4], e1[5]); bh[1].u.w = pack2(e1[6], e1[7]);
        float r0, r1, r2, r3;
        r0 = e0[0] - bfh_f(e0[0]); r1 = e0[1] - bfh_f(e0[1]);
        r2 = e0[2] - bfh_f(e0[2]); r3 = e0[3] - bfh_f(e0[3]);
        bl[0].u.x = pack2(r0, r1); bl[0].u.y = pack2(r2, r3);
        r0 = e0[4] - bfh_f(e0[4]); r1 = e0[5] - bfh_f(e0[5]);
        r2 = e0[6] - bfh_f(e0[6]); r3 = e0[7] - bfh_f(e0[7]);
        bl[0].u.z = pack2(r0, r1); bl[0].u.w = pack2(r2, r3);
        r0 = e1[0] - bfh_f(e1[0]); r1 = e1[1] - bfh_f(e1[1]);
        r2 = e1[2] - bfh_f(e1[2]); r3 = e1[3] - bfh_f(e1[3]);
        bl[1].u.x = pack2(r0, r1); bl[1].u.y = pack2(r2, r3);
        r0 = e1[4] - bfh_f(e1[4]); r1 = e1[5] - bfh_f(e1[5]);
        r2 = e1[6] - bfh_f(e1[6]); r3 = e1[7] - bfh_f(e1[7]);
        bl[1].u.z = pack2(r0, r1); bl[1].u.w = pack2(r2, r3);
        // ---- A fragments: packed, lane-consecutive (contiguous 1 KB per instr)
        U4 ah[5], al[5];
#pragma unroll
        for (int kt = 0; kt < 5; ++kt) {
            int poff = (((ch * 5 + kt) << 6) + lane) << 3;
            ah[kt].u = *reinterpret_cast<const uint4*>(&wpH[poff]);
            al[kt].u = *reinterpret_cast<const uint4*>(&wpL[poff]);
        }
#pragma unroll
        for (int kt = 0; kt < 5; ++kt)
#pragma unroll
            for (int lt = 0; lt < 2; ++lt) {
                acc[kt][lt] = __builtin_amdgcn_mfma_f32_16x16x32_bf16(ah[kt].b, bh[lt].b, acc[kt][lt], 0, 0, 0);
                acc[kt][lt] = __builtin_amdgcn_mfma_f32_16x16x32_bf16(ah[kt].b, bl[lt].b, acc[kt][lt], 0, 0, 0);
                acc[kt][lt] = __builtin_amdgcn_mfma_f32_16x16x32_bf16(al[kt].b, bh[lt].b, acc[kt][lt], 0, 0, 0);
            }
    }

    ss0 += __shfl_xor(ss0, 16, 64); ss0 += __shfl_xor(ss0, 32, 64);
    ss1 += __shfl_xor(ss1, 16, 64); ss1 += __shfl_xor(ss1, 32, 64);
    float invc[2];
    invc[0] = 1.0f / fmaxf(sqrtf(ss0), 1e-12f);
    invc[1] = 1.0f / fmaxf(sqrtf(ss1), 1e-12f);

    float4 wbv[5];
#pragma unroll
    for (int kt = 0; kt < 5; ++kt)
        wbv[kt] = *reinterpret_cast<const float4*>(&wb[kt * 16 + agrp * 4]);

    float aval[5][2][4];
    float rs[2];
#pragma unroll
    for (int lt = 0; lt < 2; ++lt) {
        float m = -1e30f;
#pragma unroll
        for (int kt = 0; kt < 5; ++kt)
#pragma unroll
            for (int r = 0; r < 4; ++r) {
                float lg = acc[kt][lt][r] * invc[lt] + ((const float*)&wbv[kt])[r];
                aval[kt][lt][r] = lg;
                m = fmaxf(m, lg);
            }
        m = fmaxf(m, __shfl_xor(m, 16, 64));
        m = fmaxf(m, __shfl_xor(m, 32, 64));
        float s = 0.f;
#pragma unroll
        for (int kt = 0; kt < 5; ++kt)
#pragma unroll
            for (int r = 0; r < 4; ++r) {
                float e = __expf(aval[kt][lt][r] - m);
                aval[kt][lt][r] = e;
                s += e;
            }
        s += __shfl_xor(s, 16, 64);
        s += __shfl_xor(s, 32, 64);
        rs[lt] = 1.0f / s;
    }

#pragma unroll
    for (int kt = 0; kt < 4; ++kt)
#pragma unroll
        for (int r = 0; r < 4; ++r) {
            int k = kt * 16 + agrp * 4 + r;
            float s01 = 0.f;
#pragma unroll
            for (int lt = 0; lt < 2; ++lt) {
                float a = aval[kt][lt][r] * rs[lt];
                aval[kt][lt][r] = a;
                s01 += a;
            }
#pragma unroll
            for (int off = 8; off; off >>= 1) s01 += __shfl_xor(s01, off, 64);
            if ((lane & 15) == 0)
                asum_part[((n * 8 + lb) * 4 + w) * KK + k] = s01;
            // packed u32 stores: both adjacent l's in one word (dense 64B segments)
            float ap0 = aval[kt][0][r] * invc[0];
            float ap1 = aval[kt][1][r] * invc[1];
            unsigned h0 = bfh(ap0), h1 = bfh(ap1);
            float q0 = ap0 - __uint_as_float(h0 << 16);
            float q1 = ap1 - __uint_as_float(h1 << 16);
            int widx = (n * KK + k) * (L_DIM / 2) + (lw0 >> 1) + arow;
            aPh32[widx] = h0 | (h1 << 16);
            aPl32[widx] = bfh(q0) | (bfh(q1) << 16);
        }
}

// ---------------- a_sum reduce ----------------
__global__ void k_asum(const float* __restrict__ part, float* __restrict__ a_sum)
{
    int id = blockIdx.x * 256 + threadIdx.x;  // 4096
    int n = id >> 6, k = id & 63;
    float s = 0.f;
#pragma unroll
    for (int p = 0; p < 32; ++p) s += part[(n * 32 + p) * KK + k];
    a_sum[id] = s;
}

// ---------------- Stage 2: vlad = a'x^T - a_sum*cent, fused rnpart, XCD swizzle ------
#define S2P 72   // LDS row pitch in shorts (144 B, 16B-aligned rows)
__global__ __launch_bounds__(256) void k_s2v(
    const float* __restrict__ x, const unsigned short* __restrict__ aPh,
    const unsigned short* __restrict__ aPl, const float* __restrict__ a_sum,
    const float* __restrict__ cent, float* __restrict__ vlad,
    float* __restrict__ rnpart)
{
    __shared__ unsigned short Ah[64 * S2P], Al[64 * S2P];   // aP chunk [k][l]
    __shared__ unsigned short Bh[64 * S2P], Bl[64 * S2P];   // x  chunk [c][l]
    __shared__ float rnbuf[4][64];

    const int flat = blockIdx.x;
    const int cq = flat >> 6;                               // 0..7
    const int n  = ((flat & 7) << 3) | ((flat >> 3) & 7);   // bijective, XCD-pinned
    const int t = threadIdx.x, lane = t & 63, w = t >> 6;
    const int arow = lane & 15, agrp = lane >> 4;

    f32x4 acc[4];
#pragma unroll
    for (int a = 0; a < 4; ++a) acc[a] = (f32x4)0.f;

    for (int step = 0; step < 16; ++step) {
        const int l0 = step * 64;
        __syncthreads();   // previous iter's reads done before restage
#pragma unroll
        for (int p = 0; p < 2; ++p) {
            int idx = p * 256 + t;          // 0..511 (512 uint4 = 4096 shorts)
            int k = idx >> 3;               // 8 uint4 per 64-short row
            int lc = (idx & 7) * 8;
            size_t g = (size_t)(n * KK + k) * L_DIM + l0 + lc;
            *reinterpret_cast<uint4*>(&Ah[k * S2P + lc]) = *reinterpret_cast<const uint4*>(&aPh[g]);
            *reinterpret_cast<uint4*>(&Al[k * S2P + lc]) = *reinterpret_cast<const uint4*>(&aPl[g]);
        }
#pragma unroll
        for (int p = 0; p < 4; ++p) {
            int idx = p * 256 + t;          // 0..1023 (1024 float4)
            int c = idx >> 4;               // 16 float4 per 64-float row
            int lc = (idx & 15) * 4;
            float4 v = *reinterpret_cast<const float4*>(
                &x[((size_t)n * C_DIM + cq * 64 + c) * L_DIM + l0 + lc]);
            uint2 hw, lw;
            hw.x = pack2(v.x, v.y); hw.y = pack2(v.z, v.w);
            float r0 = v.x - bfh_f(v.x), r1 = v.y - bfh_f(v.y);
            float r2 = v.z - bfh_f(v.z), r3 = v.w - bfh_f(v.w);
            lw.x = pack2(r0, r1); lw.y = pack2(r2, r3);
            *reinterpret_cast<uint2*>(&Bh[c * S2P + lc]) = hw;
            *reinterpret_cast<uint2*>(&Bl[c * S2P + lc]) = lw;
        }
        __syncthreads();
#pragma unroll
        for (int ks = 0; ks < 2; ++ks) {
            const int koff = ks * 32 + agrp * 8;
            U4 bh, bl;
            bh.u = *reinterpret_cast<const uint4*>(&Bh[(w * 16 + arow) * S2P + koff]);
            bl.u = *reinterpret_cast<const uint4*>(&Bl[(w * 16 + arow) * S2P + koff]);
#pragma unroll
            for (int kt = 0; kt < 4; ++kt) {
                U4 ah, al;
                ah.u = *reinterpret_cast<const uint4*>(&Ah[(kt * 16 + arow) * S2P + koff]);
                al.u = *reinterpret_cast<const uint4*>(&Al[(kt * 16 + arow) * S2P + koff]);
                acc[kt] = __builtin_amdgcn_mfma_f32_16x16x32_bf16(ah.b, bh.b, acc[kt], 0, 0, 0);
                acc[kt] = __builtin_amdgcn_mfma_f32_16x16x32_bf16(ah.b, bl.b, acc[kt], 0, 0, 0);
                acc[kt] = __builtin_amdgcn_mfma_f32_16x16x32_bf16(al.b, bh.b, acc[kt], 0, 0, 0);
            }
        }
    }
    // ---- fused epilogue: v = acc - a_sum*cent; store v; per-k sumsq partial
    const int c = cq * 64 + w * 16 + arow;
    float myrn[4][4];
#pragma unroll
    for (int kt = 0; kt < 4; ++kt)
#pragma unroll
        for (int r = 0; r < 4; ++r) {
            int k = kt * 16 + agrp * 4 + r;
            float as = a_sum[n * 64 + k];
            float cv = cent[k * C_DIM + c];
            float v = acc[kt][r] - as * cv;
            vlad[((size_t)n * KK + k) * C_DIM + c] = v;
            float sq = v * v;
            sq += __shfl_xor(sq, 1, 64);
            sq += __shfl_xor(sq, 2, 64);
            sq += __shfl_xor(sq, 4, 64);
            sq += __shfl_xor(sq, 8, 64);
            myrn[kt][r] = sq;               // valid at arow == 0
        }
    if (arow == 0) {
#pragma unroll
        for (int kt = 0; kt < 4; ++kt)
#pragma unroll
            for (int r = 0; r < 4; ++r)
                rnbuf[w][kt * 16 + agrp * 4 + r] = myrn[kt][r];
    }
    __syncthreads();
    if (t < 64) {
        float s = rnbuf[0][t] + rnbuf[1][t] + rnbuf[2][t] + rnbuf[3][t];
        rnpart[((size_t)n * 64 + t) * 8 + cq] = s;
    }
}

// ---------------- per-n scale from rnpart ----------------
__global__ void k_scale(const float* __restrict__ rnpart, float* __restrict__ scale)
{
    int n = blockIdx.x;
    int k = threadIdx.x;    // 64
    float s = 0.f;
#pragma unroll
    for (int q = 0; q < 8; ++q) s += rnpart[((size_t)n * 64 + k) * 8 + q];
    float nrm = sqrtf(s);
    float den = fmaxf(nrm, 1e-12f);
    float tk = nrm / den;
    float tot = tk * tk;
#pragma unroll
    for (int off = 32; off; off >>= 1) tot += __shfl_down(tot, off, 64);
    tot = __shfl(tot, 0, 64);
    float g = fmaxf(sqrtf(tot), 1e-12f);
    scale[n * 64 + k] = 1.0f / (den * g);
}

// ---------------- final output: v * scale ----------------
__global__ void k_out(const float* __restrict__ vlad, const float* __restrict__ scale,
                      float* __restrict__ out)
{
    int nk = blockIdx.x;
    int t = threadIdx.x;
    float sc = scale[nk];
    for (int c = t; c < C_DIM; c += 256)
        out[(size_t)nk * C_DIM + c] = vlad[(size_t)nk * C_DIM + c] * sc;
}

extern "C" void kernel_launch(void* const* d_in, const int* in_sizes, int n_in,
                              void* d_out, int out_size, void* d_ws, size_t ws_size,
                              hipStream_t stream)
{
    const float* x    = (const float*)d_in[0];
    const float* cent = (const float*)d_in[1];
    const float* cw   = (const float*)d_in[2];
    const float* cb   = (const float*)d_in[3];
    float* out = (float*)d_out;
    char* ws = (char*)d_ws;

    unsigned short* wpH = (unsigned short*)(ws + 0);                // 80 KB packed
    unsigned short* wpL = (unsigned short*)(ws + 131072);           // 80 KB packed
    float*          wb  = (float*)(ws + 262144);                    // 320 B
    unsigned short* aPh = (unsigned short*)(ws + 524288);           // 8 MB
    unsigned short* aPl = (unsigned short*)(ws + 8912896);          // 8 MB
    float* asum_part    = (float*)(ws + 17301504);                  // 512 KB
    float* a_sum        = (float*)(ws + 17825792);                  // 16 KB
    float* vlad         = (float*)(ws + 18874368);                  // 8 MB
    float* rnpart       = (float*)(ws + 27262976);                  // 128 KB
    float* scale        = (float*)(ws + 27394048);                  // 16 KB

    k_prep<<<dim3(16, 5), 256, 0, stream>>>(cw, cb, wpH, wpL, wb);
    k_s1<<<dim3(8, 64), 256, 0, stream>>>(x, wpH, wpL, wb,
                                          (unsigned*)aPh, (unsigned*)aPl, asum_part);
    k_asum<<<16, 256, 0, stream>>>(asum_part, a_sum);
    k_s2v<<<512, 256, 0, stream>>>(x, aPh, aPl, a_sum, cent, vlad, rnpart);
    k_scale<<<64, 64, 0, stream>>>(rnpart, scale);
    k_out<<<4096, 256, 0, stream>>>(vlad, scale, out);
}

// Round 18
// 76.822 us; speedup vs baseline: 1.2587x; 1.0141x over previous
//
#include <hip/hip_runtime.h>
#include <hip/hip_bf16.h>

#define C_DIM 512
#define L_DIM 1024
#define KK 64
#define KG 65
#define KP 80   // padded k rows (5 tiles of 16)

using f32x4  = __attribute__((ext_vector_type(4))) float;
using bf16x8 = __attribute__((ext_vector_type(8))) short;

union U4 { uint4 u; bf16x8 b; };

__device__ __forceinline__ unsigned bfh(float x) { return __float_as_uint(x) >> 16; }
__device__ __forceinline__ float bfh_f(float x) { return __uint_as_float(__float_as_uint(x) & 0xFFFF0000u); }

// pack two fp32 -> word of 2 bf16 (truncation): low16 = a, high16 = b
__device__ __forceinline__ unsigned pack2(float a, float b) {
    return __builtin_amdgcn_perm(__float_as_uint(b), __float_as_uint(a), 0x07060302u);
}

// ---------------- prep: split conv_w into bf16 hi/lo IN MFMA FRAGMENT ORDER ----------
__global__ void k_prep(const float* __restrict__ conv_w, const float* __restrict__ conv_b,
                       unsigned short* __restrict__ wpH, unsigned short* __restrict__ wpL,
                       float* __restrict__ wb)
{
    int ch = blockIdx.x;          // 0..15
    int kt = blockIdx.y;          // 0..4
    int t  = threadIdx.x;         // 0..255
    for (int p = 0; p < 2; ++p) {
        int idx = p * 256 + t;    // 0..511
        int lane = idx >> 3, j = idx & 7;
        int k = kt * 16 + (lane & 15);
        int c = ch * 32 + (lane >> 4) * 8 + j;
        float v = (k < KG) ? conv_w[k * C_DIM + c] : 0.f;
        unsigned h = bfh(v);
        float r = v - __uint_as_float(h << 16);
        int pos = ((ch * 5 + kt) << 9) + idx;
        wpH[pos] = (unsigned short)h;
        wpL[pos] = (unsigned short)bfh(r);
    }
    if (ch == 0 && kt == 0 && t < KP) wb[t] = (t < KG) ? conv_b[t] : -1e30f;
}

// ---------------- Stage 1: packed weights, STAGGERED chunk phase ----------------
// Grid (8 lb, 64 n), block 256 = 4 waves. Wave owns 32 l as two interleaved tiles
// (l = lw0 + 2*arow + lt); float2 x-loads feed both tiles; packed u32 aP stores.
// Chunk order rotated per wave/block: ch = (ch0 + w*4 + lb + n) & 15 so the 2048
// waves do NOT sweep the same 10KB weight slice in lockstep (L2 set contention).
__global__ __launch_bounds__(256) void k_s1(
    const float* __restrict__ x, const unsigned short* __restrict__ wpH,
    const unsigned short* __restrict__ wpL, const float* __restrict__ wb,
    unsigned* __restrict__ aPh32, unsigned* __restrict__ aPl32,
    float* __restrict__ asum_part)
{
    const int lb = blockIdx.x, n = blockIdx.y;
    const int t = threadIdx.x, lane = t & 63, w = t >> 6;
    const int arow = lane & 15;          // A/C row & B col within tile
    const int agrp = lane >> 4;          // k-slice group
    const int lw0 = lb * 128 + w * 32;   // global l base of wave
    const int choff = (w * 4 + lb + n) & 15;

    const float* xbase = x + (size_t)n * C_DIM * L_DIM;

    f32x4 acc[5][2];
#pragma unroll
    for (int a = 0; a < 5; ++a)
#pragma unroll
        for (int b = 0; b < 2; ++b) acc[a][b] = (f32x4)0.f;
    float ss0 = 0.f, ss1 = 0.f;

    for (int ch0 = 0; ch0 < 16; ++ch0) {
        const int ch = (ch0 + choff) & 15;
        const int c0 = ch * 32;
        float e0[8], e1[8];
#pragma unroll
        for (int j = 0; j < 8; ++j) {
            float2 v = *reinterpret_cast<const float2*>(
                &xbase[(size_t)(c0 + agrp * 8 + j) * L_DIM + lw0 + 2 * arow]);
            e0[j] = v.x;     // l = lw0 + 2*arow     (tile 0)
            e1[j] = v.y;     // l = lw0 + 2*arow + 1 (tile 1)
        }
#pragma unroll
        for (int j = 0; j < 8; ++j) { ss0 += e0[j] * e0[j]; ss1 += e1[j] * e1[j]; }
        U4 bh[2], bl[2];
        bh[0].u.x = pack2(e0[0], e0[1]); bh[0].u.y = pack2(e0[2], e0[3]);
        bh[0].u.z = pack2(e0[4], e0[5]); bh[0].u.w = pack2(e0[6], e0[7]);
        bh[1].u.x = pack2(e1[0], e1[1]); bh[1].u.y = pack2(e1[2], e1[3]);
        bh[1].u.z = pack2(e1[4], e1[5]); bh[1].u.w = pack2(e1[6], e1[7]);
        float r0, r1, r2, r3;
        r0 = e0[0] - bfh_f(e0[0]); r1 = e0[1] - bfh_f(e0[1]);
        r2 = e0[2] - bfh_f(e0[2]); r3 = e0[3] - bfh_f(e0[3]);
        bl[0].u.x = pack2(r0, r1); bl[0].u.y = pack2(r2, r3);
        r0 = e0[4] - bfh_f(e0[4]); r1 = e0[5] - bfh_f(e0[5]);
        r2 = e0[6] - bfh_f(e0[6]); r3 = e0[7] - bfh_f(e0[7]);
        bl[0].u.z = pack2(r0, r1); bl[0].u.w = pack2(r2, r3);
        r0 = e1[0] - bfh_f(e1[0]); r1 = e1[1] - bfh_f(e1[1]);
        r2 = e1[2] - bfh_f(e1[2]); r3 = e1[3] - bfh_f(e1[3]);
        bl[1].u.x = pack2(r0, r1); bl[1].u.y = pack2(r2, r3);
        r0 = e1[4] - bfh_f(e1[4]); r1 = e1[5] - bfh_f(e1[5]);
        r2 = e1[6] - bfh_f(e1[6]); r3 = e1[7] - bfh_f(e1[7]);
        bl[1].u.z = pack2(r0, r1); bl[1].u.w = pack2(r2, r3);
        // ---- A fragments: packed, lane-consecutive (contiguous 1 KB per instr)
        U4 ah[5], al[5];
#pragma unroll
        for (int kt = 0; kt < 5; ++kt) {
            int poff = (((ch * 5 + kt) << 6) + lane) << 3;
            ah[kt].u = *reinterpret_cast<const uint4*>(&wpH[poff]);
            al[kt].u = *reinterpret_cast<const uint4*>(&wpL[poff]);
        }
#pragma unroll
        for (int kt = 0; kt < 5; ++kt)
#pragma unroll
            for (int lt = 0; lt < 2; ++lt) {
                acc[kt][lt] = __builtin_amdgcn_mfma_f32_16x16x32_bf16(ah[kt].b, bh[lt].b, acc[kt][lt], 0, 0, 0);
                acc[kt][lt] = __builtin_amdgcn_mfma_f32_16x16x32_bf16(ah[kt].b, bl[lt].b, acc[kt][lt], 0, 0, 0);
                acc[kt][lt] = __builtin_amdgcn_mfma_f32_16x16x32_bf16(al[kt].b, bh[lt].b, acc[kt][lt], 0, 0, 0);
            }
    }

    ss0 += __shfl_xor(ss0, 16, 64); ss0 += __shfl_xor(ss0, 32, 64);
    ss1 += __shfl_xor(ss1, 16, 64); ss1 += __shfl_xor(ss1, 32, 64);
    float invc[2];
    invc[0] = 1.0f / fmaxf(sqrtf(ss0), 1e-12f);
    invc[1] = 1.0f / fmaxf(sqrtf(ss1), 1e-12f);

    float4 wbv[5];
#pragma unroll
    for (int kt = 0; kt < 5; ++kt)
        wbv[kt] = *reinterpret_cast<const float4*>(&wb[kt * 16 + agrp * 4]);

    float aval[5][2][4];
    float rs[2];
#pragma unroll
    for (int lt = 0; lt < 2; ++lt) {
        float m = -1e30f;
#pragma unroll
        for (int kt = 0; kt < 5; ++kt)
#pragma unroll
            for (int r = 0; r < 4; ++r) {
                float lg = acc[kt][lt][r] * invc[lt] + ((const float*)&wbv[kt])[r];
                aval[kt][lt][r] = lg;
                m = fmaxf(m, lg);
            }
        m = fmaxf(m, __shfl_xor(m, 16, 64));
        m = fmaxf(m, __shfl_xor(m, 32, 64));
        float s = 0.f;
#pragma unroll
        for (int kt = 0; kt < 5; ++kt)
#pragma unroll
            for (int r = 0; r < 4; ++r) {
                float e = __expf(aval[kt][lt][r] - m);
                aval[kt][lt][r] = e;
                s += e;
            }
        s += __shfl_xor(s, 16, 64);
        s += __shfl_xor(s, 32, 64);
        rs[lt] = 1.0f / s;
    }

#pragma unroll
    for (int kt = 0; kt < 4; ++kt)
#pragma unroll
        for (int r = 0; r < 4; ++r) {
            int k = kt * 16 + agrp * 4 + r;
            float s01 = 0.f;
#pragma unroll
            for (int lt = 0; lt < 2; ++lt) {
                float a = aval[kt][lt][r] * rs[lt];
                aval[kt][lt][r] = a;
                s01 += a;
            }
#pragma unroll
            for (int off = 8; off; off >>= 1) s01 += __shfl_xor(s01, off, 64);
            if ((lane & 15) == 0)
                asum_part[((n * 8 + lb) * 4 + w) * KK + k] = s01;
            // packed u32 stores: both adjacent l's in one word (dense 64B segments)
            float ap0 = aval[kt][0][r] * invc[0];
            float ap1 = aval[kt][1][r] * invc[1];
            unsigned h0 = bfh(ap0), h1 = bfh(ap1);
            float q0 = ap0 - __uint_as_float(h0 << 16);
            float q1 = ap1 - __uint_as_float(h1 << 16);
            int widx = (n * KK + k) * (L_DIM / 2) + (lw0 >> 1) + arow;
            aPh32[widx] = h0 | (h1 << 16);
            aPl32[widx] = bfh(q0) | (bfh(q1) << 16);
        }
}

// ---------------- a_sum reduce ----------------
__global__ void k_asum(const float* __restrict__ part, float* __restrict__ a_sum)
{
    int id = blockIdx.x * 256 + threadIdx.x;  // 4096
    int n = id >> 6, k = id & 63;
    float s = 0.f;
#pragma unroll
    for (int p = 0; p < 32; ++p) s += part[(n * 32 + p) * KK + k];
    a_sum[id] = s;
}

// ---------------- Stage 2: vlad = a'x^T - a_sum*cent, fused rnpart, XCD swizzle ------
#define S2P 72   // LDS row pitch in shorts (144 B, 16B-aligned rows)
__global__ __launch_bounds__(256) void k_s2v(
    const float* __restrict__ x, const unsigned short* __restrict__ aPh,
    const unsigned short* __restrict__ aPl, const float* __restrict__ a_sum,
    const float* __restrict__ cent, float* __restrict__ vlad,
    float* __restrict__ rnpart)
{
    __shared__ unsigned short Ah[64 * S2P], Al[64 * S2P];   // aP chunk [k][l]
    __shared__ unsigned short Bh[64 * S2P], Bl[64 * S2P];   // x  chunk [c][l]
    __shared__ float rnbuf[4][64];

    const int flat = blockIdx.x;
    const int cq = flat >> 6;                               // 0..7
    const int n  = ((flat & 7) << 3) | ((flat >> 3) & 7);   // bijective, XCD-pinned
    const int t = threadIdx.x, lane = t & 63, w = t >> 6;
    const int arow = lane & 15, agrp = lane >> 4;

    f32x4 acc[4];
#pragma unroll
    for (int a = 0; a < 4; ++a) acc[a] = (f32x4)0.f;

    for (int step = 0; step < 16; ++step) {
        const int l0 = step * 64;
        __syncthreads();   // previous iter's reads done before restage
#pragma unroll
        for (int p = 0; p < 2; ++p) {
            int idx = p * 256 + t;          // 0..511 (512 uint4 = 4096 shorts)
            int k = idx >> 3;               // 8 uint4 per 64-short row
            int lc = (idx & 7) * 8;
            size_t g = (size_t)(n * KK + k) * L_DIM + l0 + lc;
            *reinterpret_cast<uint4*>(&Ah[k * S2P + lc]) = *reinterpret_cast<const uint4*>(&aPh[g]);
            *reinterpret_cast<uint4*>(&Al[k * S2P + lc]) = *reinterpret_cast<const uint4*>(&aPl[g]);
        }
#pragma unroll
        for (int p = 0; p < 4; ++p) {
            int idx = p * 256 + t;          // 0..1023 (1024 float4)
            int c = idx >> 4;               // 16 float4 per 64-float row
            int lc = (idx & 15) * 4;
            float4 v = *reinterpret_cast<const float4*>(
                &x[((size_t)n * C_DIM + cq * 64 + c) * L_DIM + l0 + lc]);
            uint2 hw, lw;
            hw.x = pack2(v.x, v.y); hw.y = pack2(v.z, v.w);
            float r0 = v.x - bfh_f(v.x), r1 = v.y - bfh_f(v.y);
            float r2 = v.z - bfh_f(v.z), r3 = v.w - bfh_f(v.w);
            lw.x = pack2(r0, r1); lw.y = pack2(r2, r3);
            *reinterpret_cast<uint2*>(&Bh[c * S2P + lc]) = hw;
            *reinterpret_cast<uint2*>(&Bl[c * S2P + lc]) = lw;
        }
        __syncthreads();
#pragma unroll
        for (int ks = 0; ks < 2; ++ks) {
            const int koff = ks * 32 + agrp * 8;
            U4 bh, bl;
            bh.u = *reinterpret_cast<const uint4*>(&Bh[(w * 16 + arow) * S2P + koff]);
            bl.u = *reinterpret_cast<const uint4*>(&Bl[(w * 16 + arow) * S2P + koff]);
#pragma unroll
            for (int kt = 0; kt < 4; ++kt) {
                U4 ah, al;
                ah.u = *reinterpret_cast<const uint4*>(&Ah[(kt * 16 + arow) * S2P + koff]);
                al.u = *reinterpret_cast<const uint4*>(&Al[(kt * 16 + arow) * S2P + koff]);
                acc[kt] = __builtin_amdgcn_mfma_f32_16x16x32_bf16(ah.b, bh.b, acc[kt], 0, 0, 0);
                acc[kt] = __builtin_amdgcn_mfma_f32_16x16x32_bf16(ah.b, bl.b, acc[kt], 0, 0, 0);
                acc[kt] = __builtin_amdgcn_mfma_f32_16x16x32_bf16(al.b, bh.b, acc[kt], 0, 0, 0);
            }
        }
    }
    // ---- fused epilogue: v = acc - a_sum*cent; store v; per-k sumsq partial
    const int c = cq * 64 + w * 16 + arow;
    float myrn[4][4];
#pragma unroll
    for (int kt = 0; kt < 4; ++kt)
#pragma unroll
        for (int r = 0; r < 4; ++r) {
            int k = kt * 16 + agrp * 4 + r;
            float as = a_sum[n * 64 + k];
            float cv = cent[k * C_DIM + c];
            float v = acc[kt][r] - as * cv;
            vlad[((size_t)n * KK + k) * C_DIM + c] = v;
            float sq = v * v;
            sq += __shfl_xor(sq, 1, 64);
            sq += __shfl_xor(sq, 2, 64);
            sq += __shfl_xor(sq, 4, 64);
            sq += __shfl_xor(sq, 8, 64);
            myrn[kt][r] = sq;               // valid at arow == 0
        }
    if (arow == 0) {
#pragma unroll
        for (int kt = 0; kt < 4; ++kt)
#pragma unroll
            for (int r = 0; r < 4; ++r)
                rnbuf[w][kt * 16 + agrp * 4 + r] = myrn[kt][r];
    }
    __syncthreads();
    if (t < 64) {
        float s = rnbuf[0][t] + rnbuf[1][t] + rnbuf[2][t] + rnbuf[3][t];
        rnpart[((size_t)n * 64 + t) * 8 + cq] = s;
    }
}

// ---------------- per-n scale from rnpart ----------------
__global__ void k_scale(const float* __restrict__ rnpart, float* __restrict__ scale)
{
    int n = blockIdx.x;
    int k = threadIdx.x;    // 64
    float s = 0.f;
#pragma unroll
    for (int q = 0; q < 8; ++q) s += rnpart[((size_t)n * 64 + k) * 8 + q];
    float nrm = sqrtf(s);
    float den = fmaxf(nrm, 1e-12f);
    float tk = nrm / den;
    float tot = tk * tk;
#pragma unroll
    for (int off = 32; off; off >>= 1) tot += __shfl_down(tot, off, 64);
    tot = __shfl(tot, 0, 64);
    float g = fmaxf(sqrtf(tot), 1e-12f);
    scale[n * 64 + k] = 1.0f / (den * g);
}

// ---------------- final output: v * scale ----------------
__global__ void k_out(const float* __restrict__ vlad, const float* __restrict__ scale,
                      float* __restrict__ out)
{
    int nk = blockIdx.x;
    int t = threadIdx.x;
    float sc = scale[nk];
    for (int c = t; c < C_DIM; c += 256)
        out[(size_t)nk * C_DIM + c] = vlad[(size_t)nk * C_DIM + c] * sc;
}

extern "C" void kernel_launch(void* const* d_in, const int* in_sizes, int n_in,
                              void* d_out, int out_size, void* d_ws, size_t ws_size,
                              hipStream_t stream)
{
    const float* x    = (const float*)d_in[0];
    const float* cent = (const float*)d_in[1];
    const float* cw   = (const float*)d_in[2];
    const float* cb   = (const float*)d_in[3];
    float* out = (float*)d_out;
    char* ws = (char*)d_ws;

    unsigned short* wpH = (unsigned short*)(ws + 0);                // 80 KB packed
    unsigned short* wpL = (unsigned short*)(ws + 131072);           // 80 KB packed
    float*          wb  = (float*)(ws + 262144);                    // 320 B
    unsigned short* aPh = (unsigned short*)(ws + 524288);           // 8 MB
    unsigned short* aPl = (unsigned short*)(ws + 8912896);          // 8 MB
    float* asum_part    = (float*)(ws + 17301504);                  // 512 KB
    float* a_sum        = (float*)(ws + 17825792);                  // 16 KB
    float* vlad         = (float*)(ws + 18874368);                  // 8 MB
    float* rnpart       = (float*)(ws + 27262976);                  // 128 KB
    float* scale        = (float*)(ws + 27394048);                  // 16 KB

    k_prep<<<dim3(16, 5), 256, 0, stream>>>(cw, cb, wpH, wpL, wb);
    k_s1<<<dim3(8, 64), 256, 0, stream>>>(x, wpH, wpL, wb,
                                          (unsigned*)aPh, (unsigned*)aPl, asum_part);
    k_asum<<<16, 256, 0, stream>>>(asum_part, a_sum);
    k_s2v<<<512, 256, 0, stream>>>(x, aPh, aPl, a_sum, cent, vlad, rnpart);
    k_scale<<<64, 64, 0, stream>>>(rnpart, scale);
    k_out<<<4096, 256, 0, stream>>>(vlad, scale, out);
}